// Round 6
// baseline (154.349 us; speedup 1.0000x reference)
//
#include <hip/hip_runtime.h>

#define N_NODES 65536
#define N_EDGES 1048576
#define D 64
#define NB 256                  // major buckets = dst >> 8
#define CHUNK (N_EDGES / NB)    // 4096 edges per histA/scatterA workgroup

typedef __bf16 bf16x8 __attribute__((ext_vector_type(8)));
typedef float f32x4 __attribute__((ext_vector_type(4)));

// ---------------------------------------------------------------------------
// Detect int64 vs int32 edge_index delivery — parallel, one round-trip.
// int64 values < 2^17 => hi word of every element is 0.
// ---------------------------------------------------------------------------
__global__ void detect_kernel(const unsigned* ei, int* flag) {
    unsigned v = ei[2 * threadIdx.x + 1];
    unsigned long long nz = __ballot(v != 0u);
    if (threadIdx.x == 0) *flag = (nz == 0ull) ? 1 : 0;
}

__device__ __forceinline__ int edge_at(const void* ei, int is64, long long pos) {
    if (is64) return (int)((const long long*)ei)[pos];
    return ((const int*)ei)[pos];
}

// Pass A1: per-chunk histogram over dst>>8. H layout: H[bucket*NB + wg].
__global__ __launch_bounds__(256) void histA_kernel(const void* ei, const int* flag,
                                                    unsigned* __restrict__ H) {
    __shared__ unsigned hist[NB];
    const int is64 = *flag;
    const int t = threadIdx.x;
    const int w = blockIdx.x;
    hist[t] = 0;
    __syncthreads();
    const int base = w * CHUNK;
    for (int i = t; i < CHUNK; i += 256) {
        int dst = edge_at(ei, is64, (long long)N_EDGES + base + i);
        atomicAdd(&hist[dst >> 8], 1u);
    }
    __syncthreads();
    H[t * NB + w] = hist[t];
}

// Pass A2: one WG. Thread b: serial exclusive prefix over H[b][*] -> P[b][*],
// then block-scan of bucket totals -> bucket_start[257].
__global__ __launch_bounds__(256) void scanH_kernel(const unsigned* __restrict__ H,
                                                    unsigned* __restrict__ P,
                                                    unsigned* __restrict__ bucket_start) {
    __shared__ unsigned cs[NB];
    const int b = threadIdx.x;
    unsigned run = 0;
#pragma unroll 8
    for (int w = 0; w < NB; ++w) {
        P[b * NB + w] = run;
        run += H[b * NB + w];
    }
    unsigned own = run;
    cs[b] = run;
    __syncthreads();
    for (int off = 1; off < NB; off <<= 1) {
        unsigned v = (b >= off) ? cs[b - off] : 0u;
        __syncthreads();
        cs[b] += v;
        __syncthreads();
    }
    bucket_start[b] = cs[b] - own;
    if (b == NB - 1) bucket_start[NB] = cs[b];
}

// Pass A3: scatter edges into bucket-major order as packed u32:
// src in bits [0,16), dst&255 in bits [16,24). LDS cursors only.
__global__ __launch_bounds__(256) void scatterA_kernel(const void* ei, const int* flag,
                                                       const unsigned* __restrict__ P,
                                                       const unsigned* __restrict__ bucket_start,
                                                       unsigned* __restrict__ pairs) {
    __shared__ unsigned cur[NB];
    const int is64 = *flag;
    const int t = threadIdx.x;
    const int w = blockIdx.x;
    cur[t] = bucket_start[t] + P[t * NB + w];
    __syncthreads();
    const int base = w * CHUNK;
    for (int i = t; i < CHUNK; i += 256) {
        int src = edge_at(ei, is64, base + i);
        int dst = edge_at(ei, is64, (long long)N_EDGES + base + i);
        unsigned pos = atomicAdd(&cur[dst >> 8], 1u);
        pairs[pos] = (unsigned)src | ((unsigned)(dst & 255) << 16);
    }
}

// Pass B: per major bucket: LDS histogram over dstlow (== deg, written
// densely), LDS scan -> row_start, LDS-cursor scatter -> final src_sorted.
__global__ __launch_bounds__(256) void bucketB_kernel(const unsigned* __restrict__ pairs,
                                                      const unsigned* __restrict__ bucket_start,
                                                      unsigned* __restrict__ deg,
                                                      unsigned* __restrict__ row_start,
                                                      int* __restrict__ src_sorted) {
    __shared__ unsigned hist[NB];
    __shared__ unsigned sc[NB];
    const int t = threadIdx.x;
    const int b = blockIdx.x;
    const unsigned base = bucket_start[b];
    const unsigned cnt = bucket_start[b + 1] - base;
    hist[t] = 0;
    __syncthreads();
    for (unsigned i = t; i < cnt; i += 256u) {
        atomicAdd(&hist[(pairs[base + i] >> 16) & 255u], 1u);
    }
    __syncthreads();
    const unsigned own = hist[t];
    deg[b * NB + t] = own;
    sc[t] = own;
    __syncthreads();
    for (int off = 1; off < NB; off <<= 1) {
        unsigned v = (t >= off) ? sc[t - off] : 0u;
        __syncthreads();
        sc[t] += v;
        __syncthreads();
    }
    const unsigned excl = sc[t] - own;
    row_start[b * NB + t] = base + excl;
    if (b == NB - 1 && t == 0) row_start[N_NODES] = N_EDGES;
    hist[t] = excl;  // reuse as cursor
    __syncthreads();
    for (unsigned i = t; i < cnt; i += 256u) {
        unsigned p = pairs[base + i];
        unsigned pos = atomicAdd(&hist[(p >> 16) & 255u], 1u);
        src_sorted[base + pos] = (int)(p & 0xFFFFu);
    }
}

// y[n][d] = bf16( rsqrt(deg[n]) * x[n][d] ) — prefolded source weight.
__global__ __launch_bounds__(256) void y_kernel(const float* __restrict__ x,
                                                const unsigned* __restrict__ deg,
                                                unsigned* __restrict__ y32) {
    int idx = blockIdx.x * blockDim.x + threadIdx.x;  // 0 .. N_NODES*32
    int n = idx >> 5;
    int c = (idx & 31) * 2;
    unsigned d = deg[n];
    float w = d ? rsqrtf((float)d) : 0.f;
    float2 v = *(const float2*)(x + n * D + c);
    unsigned lo = (unsigned)__builtin_bit_cast(unsigned short, (__bf16)(v.x * w));
    unsigned hi = (unsigned)__builtin_bit_cast(unsigned short, (__bf16)(v.y * w));
    y32[idx] = lo | (hi << 16);
}

// ---------------------------------------------------------------------------
// Fused SpMM + dense: each wave owns 16 consecutive nodes.
// SpMM phase: 4 edges in flight (16-lane groups), each lane loads dwordx2
// (4 bf16 feats) of prefolded y; 8 independent accumulators; cross-group
// combine via shfl_xor(16/32); h row -> LDS tile [16][68] (padded).
// Dense phase: A-frags from LDS, x-frags from global, 16 MFMAs, epilogue.
// ---------------------------------------------------------------------------
__global__ __launch_bounds__(256) void fused_kernel(const int* __restrict__ src_sorted,
                                                    const unsigned* __restrict__ row_start,
                                                    const unsigned* __restrict__ y32,
                                                    const float* __restrict__ x,
                                                    const float* __restrict__ W1,
                                                    const float* __restrict__ b1,
                                                    const float* __restrict__ W2,
                                                    const float* __restrict__ b2,
                                                    float* __restrict__ out) {
    __shared__ alignas(16) float hs[4][16][68];
    const int lane = threadIdx.x & 63;
    const int wv = threadIdx.x >> 6;
    const int grp = lane >> 4;   // edge slot 0..3
    const int r16 = lane & 15;   // feature quarter: u32 cols 2*r16, 2*r16+1
    const int lo = lane & 15;    // MFMA row / col-within-16
    const int hi = lane >> 4;    // MFMA k-chunk / row group

    // Preload B-frags for W1/W2 and biases (register-resident).
    bf16x8 bw1[2][4], bw2[2][4];
#pragma unroll
    for (int kt = 0; kt < 2; ++kt)
#pragma unroll
        for (int nt = 0; nt < 4; ++nt) {
            bf16x8 v1, v2;
#pragma unroll
            for (int j = 0; j < 8; ++j) {
                int k = kt * 32 + hi * 8 + j;
                int n = nt * 16 + lo;
                v1[j] = (__bf16)W1[k * D + n];
                v2[j] = (__bf16)W2[k * D + n];
            }
            bw1[kt][nt] = v1;
            bw2[kt][nt] = v2;
        }
    float bb1[4], bb2[4];
#pragma unroll
    for (int nt = 0; nt < 4; ++nt) {
        bb1[nt] = b1[nt * 16 + lo];
        bb2[nt] = b2[nt * 16 + lo];
    }

    const int rb = (blockIdx.x * 4 + wv) * 16;  // grid sized exactly: 1024 blocks

    // ---- SpMM phase ----
    for (int rr = 0; rr < 16; ++rr) {
        const int n = rb + rr;
        const unsigned start = row_start[n];
        const unsigned end = row_start[n + 1];
        float a0 = 0.f, a1 = 0.f, a2 = 0.f, a3 = 0.f;
        float c0 = 0.f, c1 = 0.f, c2 = 0.f, c3 = 0.f;
        unsigned i = start;
        for (; i + 8 <= end; i += 8) {
            int sA = src_sorted[i + grp];
            int sB = src_sorted[i + 4 + grp];
            uint2 pA = *(const uint2*)(y32 + sA * 32 + r16 * 2);
            uint2 pB = *(const uint2*)(y32 + sB * 32 + r16 * 2);
            a0 += __uint_as_float(pA.x << 16);
            a1 += __uint_as_float(pA.x & 0xffff0000u);
            a2 += __uint_as_float(pA.y << 16);
            a3 += __uint_as_float(pA.y & 0xffff0000u);
            c0 += __uint_as_float(pB.x << 16);
            c1 += __uint_as_float(pB.x & 0xffff0000u);
            c2 += __uint_as_float(pB.y << 16);
            c3 += __uint_as_float(pB.y & 0xffff0000u);
        }
        for (; i < end; i += 4) {
            if (i + grp < end) {
                int s = src_sorted[i + grp];
                uint2 p = *(const uint2*)(y32 + s * 32 + r16 * 2);
                a0 += __uint_as_float(p.x << 16);
                a1 += __uint_as_float(p.x & 0xffff0000u);
                a2 += __uint_as_float(p.y << 16);
                a3 += __uint_as_float(p.y & 0xffff0000u);
            }
        }
        a0 += c0; a1 += c1; a2 += c2; a3 += c3;
        a0 += __shfl_xor(a0, 16); a0 += __shfl_xor(a0, 32);
        a1 += __shfl_xor(a1, 16); a1 += __shfl_xor(a1, 32);
        a2 += __shfl_xor(a2, 16); a2 += __shfl_xor(a2, 32);
        a3 += __shfl_xor(a3, 16); a3 += __shfl_xor(a3, 32);
        const float w = (end > start) ? rsqrtf((float)(end - start)) : 0.f;
        if (grp == 0) {
            float4 v = make_float4(a0 * w, a1 * w, a2 * w, a3 * w);
            *(float4*)(&hs[wv][rr][r16 * 4]) = v;
        }
    }
    __syncthreads();

    // ---- Dense phase ----
    const float* xrow = x + (rb + lo) * D;
    bf16x8 ah[2], ag[2];
#pragma unroll
    for (int kt = 0; kt < 2; ++kt) {
        const int c = kt * 32 + hi * 8;
        float4 h0 = *(const float4*)(&hs[wv][lo][c]);
        float4 h1 = *(const float4*)(&hs[wv][lo][c + 4]);
        float4 xv0 = *(const float4*)(xrow + c);
        float4 xv1 = *(const float4*)(xrow + c + 4);
        bf16x8 a, g;
        a[0] = (__bf16)h0.x; g[0] = (__bf16)(h0.x * xv0.x);
        a[1] = (__bf16)h0.y; g[1] = (__bf16)(h0.y * xv0.y);
        a[2] = (__bf16)h0.z; g[2] = (__bf16)(h0.z * xv0.z);
        a[3] = (__bf16)h0.w; g[3] = (__bf16)(h0.w * xv0.w);
        a[4] = (__bf16)h1.x; g[4] = (__bf16)(h1.x * xv1.x);
        a[5] = (__bf16)h1.y; g[5] = (__bf16)(h1.y * xv1.y);
        a[6] = (__bf16)h1.z; g[6] = (__bf16)(h1.z * xv1.z);
        a[7] = (__bf16)h1.w; g[7] = (__bf16)(h1.w * xv1.w);
        ah[kt] = a;
        ag[kt] = g;
    }
    f32x4 acc1[4], acc2[4];
#pragma unroll
    for (int nt = 0; nt < 4; ++nt) {
        acc1[nt] = (f32x4){0.f, 0.f, 0.f, 0.f};
        acc2[nt] = (f32x4){0.f, 0.f, 0.f, 0.f};
    }
#pragma unroll
    for (int kt = 0; kt < 2; ++kt)
#pragma unroll
        for (int nt = 0; nt < 4; ++nt) {
            acc1[nt] = __builtin_amdgcn_mfma_f32_16x16x32_bf16(ah[kt], bw1[kt][nt], acc1[nt], 0, 0, 0);
            acc2[nt] = __builtin_amdgcn_mfma_f32_16x16x32_bf16(ag[kt], bw2[kt][nt], acc2[nt], 0, 0, 0);
        }
#pragma unroll
    for (int nt = 0; nt < 4; ++nt)
#pragma unroll
        for (int r = 0; r < 4; ++r) {
            float v1 = acc1[nt][r] + bb1[nt];
            float v2 = acc2[nt][r] + bb2[nt];
            v1 = (v1 >= 0.f) ? v1 : 0.2f * v1;
            v2 = (v2 >= 0.f) ? v2 : 0.2f * v2;
            out[(rb + hi * 4 + r) * D + nt * 16 + lo] = v1 + v2;
        }
}

extern "C" void kernel_launch(void* const* d_in, const int* in_sizes, int n_in,
                              void* d_out, int out_size, void* d_ws, size_t ws_size,
                              hipStream_t stream) {
    const float* x  = (const float*)d_in[0];
    const void*  ei = d_in[1];
    const float* W1 = (const float*)d_in[2];
    const float* b1 = (const float*)d_in[3];
    const float* W2 = (const float*)d_in[4];
    const float* b2 = (const float*)d_in[5];
    float* out = (float*)d_out;

    char* ws = (char*)d_ws;
    const size_t K = (size_t)N_NODES * 4;  // 256 KB
    int*      flag         = (int*)ws;                          // 256 B
    unsigned* deg          = (unsigned*)(ws + 256);             // K
    unsigned* row_start    = (unsigned*)(ws + 256 + K);         // K + 256 (65537)
    unsigned* H            = (unsigned*)(ws + 512 + 2 * K);     // K
    unsigned* P            = (unsigned*)(ws + 512 + 3 * K);     // K
    unsigned* bucket_start = (unsigned*)(ws + 512 + 4 * K);     // 1028 B (pad 2KB)
    int*      src_sorted   = (int*)(ws + 2560 + 4 * K);         // 4 MB
    unsigned* y32          = (unsigned*)(ws + 2560 + 4 * K + (size_t)N_EDGES * 4);  // 8 MB

    // pairs scratch lives in d_out: written by scatterA, consumed by bucketB,
    // then fully overwritten by fused_kernel's out. Deterministic.
    unsigned* pairs = (unsigned*)d_out;

    detect_kernel<<<1, 64, 0, stream>>>((const unsigned*)ei, flag);
    histA_kernel<<<NB, 256, 0, stream>>>(ei, flag, H);
    scanH_kernel<<<1, 256, 0, stream>>>(H, P, bucket_start);
    scatterA_kernel<<<NB, 256, 0, stream>>>(ei, flag, P, bucket_start, pairs);
    bucketB_kernel<<<NB, 256, 0, stream>>>(pairs, bucket_start, deg, row_start, src_sorted);
    y_kernel<<<N_NODES * 32 / 256, 256, 0, stream>>>(x, deg, y32);
    fused_kernel<<<N_NODES / 64, 256, 0, stream>>>(src_sorted, row_start, y32, x,
                                                   W1, b1, W2, b2, out);
}

// Round 7
// 112.006 us; speedup vs baseline: 1.3780x; 1.3780x over previous
//
#include <hip/hip_runtime.h>

#define N_NODES 65536
#define N_EDGES 1048576
#define D 64
#define NB 256                  // major buckets = dst >> 8
#define CHUNK (N_EDGES / NB)    // 4096 edges per histA/scatterA workgroup

typedef __bf16 bf16x8 __attribute__((ext_vector_type(8)));
typedef float f32x4 __attribute__((ext_vector_type(4)));

// ---------------------------------------------------------------------------
// Detect int64 vs int32 edge_index delivery — parallel, one round-trip.
// ---------------------------------------------------------------------------
__global__ void detect_kernel(const unsigned* ei, int* flag) {
    unsigned v = ei[2 * threadIdx.x + 1];
    unsigned long long nz = __ballot(v != 0u);
    if (threadIdx.x == 0) *flag = (nz == 0ull) ? 1 : 0;
}

__device__ __forceinline__ int edge_at(const void* ei, int is64, long long pos) {
    if (is64) return (int)((const long long*)ei)[pos];
    return ((const int*)ei)[pos];
}

// Pass A1: per-chunk histogram over dst>>8. H layout: H[bucket*NB + wg].
__global__ __launch_bounds__(256) void histA_kernel(const void* ei, const int* flag,
                                                    unsigned* __restrict__ H) {
    __shared__ unsigned hist[NB];
    const int is64 = *flag;
    const int t = threadIdx.x;
    const int w = blockIdx.x;
    hist[t] = 0;
    __syncthreads();
    const int base = w * CHUNK;
    for (int i = t; i < CHUNK; i += 256) {
        int dst = edge_at(ei, is64, (long long)N_EDGES + base + i);
        atomicAdd(&hist[dst >> 8], 1u);
    }
    __syncthreads();
    H[t * NB + w] = hist[t];
}

// Pass A2: one WG. Thread b: serial exclusive prefix over H[b][*] -> P[b][*],
// then block-scan of bucket totals -> bucket_start[257].
__global__ __launch_bounds__(256) void scanH_kernel(const unsigned* __restrict__ H,
                                                    unsigned* __restrict__ P,
                                                    unsigned* __restrict__ bucket_start) {
    __shared__ unsigned cs[NB];
    const int b = threadIdx.x;
    unsigned run = 0;
#pragma unroll 8
    for (int w = 0; w < NB; ++w) {
        P[b * NB + w] = run;
        run += H[b * NB + w];
    }
    unsigned own = run;
    cs[b] = run;
    __syncthreads();
    for (int off = 1; off < NB; off <<= 1) {
        unsigned v = (b >= off) ? cs[b - off] : 0u;
        __syncthreads();
        cs[b] += v;
        __syncthreads();
    }
    bucket_start[b] = cs[b] - own;
    if (b == NB - 1) bucket_start[NB] = cs[b];
}

// Pass A3: scatter edges into bucket-major order as packed u32:
// src in bits [0,16), dst&255 in bits [16,24). LDS cursors only.
__global__ __launch_bounds__(256) void scatterA_kernel(const void* ei, const int* flag,
                                                       const unsigned* __restrict__ P,
                                                       const unsigned* __restrict__ bucket_start,
                                                       unsigned* __restrict__ pairs) {
    __shared__ unsigned cur[NB];
    const int is64 = *flag;
    const int t = threadIdx.x;
    const int w = blockIdx.x;
    cur[t] = bucket_start[t] + P[t * NB + w];
    __syncthreads();
    const int base = w * CHUNK;
    for (int i = t; i < CHUNK; i += 256) {
        int src = edge_at(ei, is64, base + i);
        int dst = edge_at(ei, is64, (long long)N_EDGES + base + i);
        unsigned pos = atomicAdd(&cur[dst >> 8], 1u);
        pairs[pos] = (unsigned)src | ((unsigned)(dst & 255) << 16);
    }
}

// Pass B: per major bucket: LDS histogram over dstlow (== deg, dense),
// LDS scan -> row_start, LDS-cursor scatter -> src_sorted, then the
// prefolded y rows for this bucket's 256 nodes (deg is already in LDS).
__global__ __launch_bounds__(256) void bucketB_kernel(const unsigned* __restrict__ pairs,
                                                      const unsigned* __restrict__ bucket_start,
                                                      const float* __restrict__ x,
                                                      unsigned* __restrict__ row_start,
                                                      int* __restrict__ src_sorted,
                                                      unsigned* __restrict__ y32) {
    __shared__ unsigned hist[NB];
    __shared__ unsigned sc[NB];
    __shared__ unsigned degs[NB];
    const int t = threadIdx.x;
    const int b = blockIdx.x;
    const unsigned base = bucket_start[b];
    const unsigned cnt = bucket_start[b + 1] - base;
    hist[t] = 0;
    __syncthreads();
    for (unsigned i = t; i < cnt; i += 256u) {
        atomicAdd(&hist[(pairs[base + i] >> 16) & 255u], 1u);
    }
    __syncthreads();
    const unsigned own = hist[t];
    degs[t] = own;
    sc[t] = own;
    __syncthreads();
    for (int off = 1; off < NB; off <<= 1) {
        unsigned v = (t >= off) ? sc[t - off] : 0u;
        __syncthreads();
        sc[t] += v;
        __syncthreads();
    }
    const unsigned excl = sc[t] - own;
    row_start[b * NB + t] = base + excl;
    if (b == NB - 1 && t == 0) row_start[N_NODES] = N_EDGES;
    hist[t] = excl;  // reuse as cursor
    __syncthreads();
    for (unsigned i = t; i < cnt; i += 256u) {
        unsigned p = pairs[base + i];
        unsigned pos = atomicAdd(&hist[(p >> 16) & 255u], 1u);
        src_sorted[base + pos] = (int)(p & 0xFFFFu);
    }
    // y phase: y[n][d] = bf16(rsqrt(deg[n]) * x[n][d]) for n in this bucket.
    const int nbase = b * NB;
    for (int idx = t; idx < NB * 32; idx += 256) {
        int nl = idx >> 5;
        int c = (idx & 31) * 2;
        unsigned d = degs[nl];
        float w = d ? rsqrtf((float)d) : 0.f;
        float2 v = *(const float2*)(x + (nbase + nl) * D + c);
        unsigned lo = (unsigned)__builtin_bit_cast(unsigned short, (__bf16)(v.x * w));
        unsigned hi = (unsigned)__builtin_bit_cast(unsigned short, (__bf16)(v.y * w));
        y32[(nbase + nl) * 32 + (idx & 31)] = lo | (hi << 16);
    }
}

// Atomic-free segmented SpMM over prefolded bf16 y.
// Wave = 4 groups x 16 lanes: group g handles edge slot g, lane r16 loads
// uint2 (4 bf16 feats). One gather instr covers 4 rows x 128B = 512B.
// Combine via shfl_xor(16,32); h[n] = rsqrt(deg_n) * sum. Skinny kernel:
// low VGPR, 16384 waves for latency hiding.
__global__ __launch_bounds__(256) void spmm_kernel(const int* __restrict__ src_sorted,
                                                   const unsigned* __restrict__ row_start,
                                                   const unsigned* __restrict__ y32,
                                                   float* __restrict__ h) {
    const int lane = threadIdx.x & 63;
    const int grp = lane >> 4;
    const int r16 = lane & 15;
    int wid = (blockIdx.x * blockDim.x + threadIdx.x) >> 6;
    int nw = (gridDim.x * blockDim.x) >> 6;
    for (int n = wid; n < N_NODES; n += nw) {
        const unsigned start = row_start[n];
        const unsigned end = row_start[n + 1];
        float a0 = 0.f, a1 = 0.f, a2 = 0.f, a3 = 0.f;
        float c0 = 0.f, c1 = 0.f, c2 = 0.f, c3 = 0.f;
        unsigned i = start;
        for (; i + 8 <= end; i += 8) {
            int sA = src_sorted[i + grp];
            int sB = src_sorted[i + 4 + grp];
            uint2 pA = *(const uint2*)(y32 + sA * 32 + r16 * 2);
            uint2 pB = *(const uint2*)(y32 + sB * 32 + r16 * 2);
            a0 += __uint_as_float(pA.x << 16);
            a1 += __uint_as_float(pA.x & 0xffff0000u);
            a2 += __uint_as_float(pA.y << 16);
            a3 += __uint_as_float(pA.y & 0xffff0000u);
            c0 += __uint_as_float(pB.x << 16);
            c1 += __uint_as_float(pB.x & 0xffff0000u);
            c2 += __uint_as_float(pB.y << 16);
            c3 += __uint_as_float(pB.y & 0xffff0000u);
        }
        for (; i < end; i += 4) {
            if (i + grp < end) {
                int s = src_sorted[i + grp];
                uint2 p = *(const uint2*)(y32 + s * 32 + r16 * 2);
                a0 += __uint_as_float(p.x << 16);
                a1 += __uint_as_float(p.x & 0xffff0000u);
                a2 += __uint_as_float(p.y << 16);
                a3 += __uint_as_float(p.y & 0xffff0000u);
            }
        }
        a0 += c0; a1 += c1; a2 += c2; a3 += c3;
        a0 += __shfl_xor(a0, 16); a0 += __shfl_xor(a0, 32);
        a1 += __shfl_xor(a1, 16); a1 += __shfl_xor(a1, 32);
        a2 += __shfl_xor(a2, 16); a2 += __shfl_xor(a2, 32);
        a3 += __shfl_xor(a3, 16); a3 += __shfl_xor(a3, 32);
        const float w = (end > start) ? rsqrtf((float)(end - start)) : 0.f;
        if (grp == 0) {
            float4 v = make_float4(a0 * w, a1 * w, a2 * w, a3 * w);
            *(float4*)(h + n * D + r16 * 4) = v;
        }
    }
}

// out = leaky(h@W1+b1) + leaky((x*h)@W2+b2) via mfma_f32_16x16x32_bf16.
__global__ __launch_bounds__(256) void dense_mfma_kernel(const float* __restrict__ x,
                                                         const float* __restrict__ W1,
                                                         const float* __restrict__ b1,
                                                         const float* __restrict__ W2,
                                                         const float* __restrict__ b2,
                                                         float* hout) {
    const int lane = threadIdx.x & 63;
    const int lo = lane & 15;
    const int hi = lane >> 4;

    bf16x8 bw1[2][4], bw2[2][4];
#pragma unroll
    for (int kt = 0; kt < 2; ++kt)
#pragma unroll
        for (int nt = 0; nt < 4; ++nt) {
            bf16x8 v1, v2;
#pragma unroll
            for (int j = 0; j < 8; ++j) {
                int k = kt * 32 + hi * 8 + j;
                int n = nt * 16 + lo;
                v1[j] = (__bf16)W1[k * D + n];
                v2[j] = (__bf16)W2[k * D + n];
            }
            bw1[kt][nt] = v1;
            bw2[kt][nt] = v2;
        }
    float bb1[4], bb2[4];
#pragma unroll
    for (int nt = 0; nt < 4; ++nt) {
        bb1[nt] = b1[nt * 16 + lo];
        bb2[nt] = b2[nt * 16 + lo];
    }

    int wid = (blockIdx.x * blockDim.x + threadIdx.x) >> 6;
    int nw = (gridDim.x * blockDim.x) >> 6;
    for (int blk = wid; blk < N_NODES / 16; blk += nw) {
        const int rb = blk * 16;
        const float* hrow = hout + (rb + lo) * D;
        const float* xrow = x + (rb + lo) * D;
        bf16x8 ah[2], ag[2];
#pragma unroll
        for (int kt = 0; kt < 2; ++kt) {
            const int c = kt * 32 + hi * 8;
            float4 hv0 = *(const float4*)(hrow + c);
            float4 hv1 = *(const float4*)(hrow + c + 4);
            float4 xv0 = *(const float4*)(xrow + c);
            float4 xv1 = *(const float4*)(xrow + c + 4);
            bf16x8 a, g;
            a[0] = (__bf16)hv0.x; g[0] = (__bf16)(hv0.x * xv0.x);
            a[1] = (__bf16)hv0.y; g[1] = (__bf16)(hv0.y * xv0.y);
            a[2] = (__bf16)hv0.z; g[2] = (__bf16)(hv0.z * xv0.z);
            a[3] = (__bf16)hv0.w; g[3] = (__bf16)(hv0.w * xv0.w);
            a[4] = (__bf16)hv1.x; g[4] = (__bf16)(hv1.x * xv1.x);
            a[5] = (__bf16)hv1.y; g[5] = (__bf16)(hv1.y * xv1.y);
            a[6] = (__bf16)hv1.z; g[6] = (__bf16)(hv1.z * xv1.z);
            a[7] = (__bf16)hv1.w; g[7] = (__bf16)(hv1.w * xv1.w);
            ah[kt] = a;
            ag[kt] = g;
        }
        f32x4 acc1[4], acc2[4];
#pragma unroll
        for (int nt = 0; nt < 4; ++nt) {
            acc1[nt] = (f32x4){0.f, 0.f, 0.f, 0.f};
            acc2[nt] = (f32x4){0.f, 0.f, 0.f, 0.f};
        }
#pragma unroll
        for (int kt = 0; kt < 2; ++kt)
#pragma unroll
            for (int nt = 0; nt < 4; ++nt) {
                acc1[nt] = __builtin_amdgcn_mfma_f32_16x16x32_bf16(ah[kt], bw1[kt][nt], acc1[nt], 0, 0, 0);
                acc2[nt] = __builtin_amdgcn_mfma_f32_16x16x32_bf16(ag[kt], bw2[kt][nt], acc2[nt], 0, 0, 0);
            }
#pragma unroll
        for (int nt = 0; nt < 4; ++nt)
#pragma unroll
            for (int r = 0; r < 4; ++r) {
                float a1 = acc1[nt][r] + bb1[nt];
                float a2 = acc2[nt][r] + bb2[nt];
                a1 = (a1 >= 0.f) ? a1 : 0.2f * a1;
                a2 = (a2 >= 0.f) ? a2 : 0.2f * a2;
                hout[(rb + hi * 4 + r) * D + nt * 16 + lo] = a1 + a2;
            }
    }
}

extern "C" void kernel_launch(void* const* d_in, const int* in_sizes, int n_in,
                              void* d_out, int out_size, void* d_ws, size_t ws_size,
                              hipStream_t stream) {
    const float* x  = (const float*)d_in[0];
    const void*  ei = d_in[1];
    const float* W1 = (const float*)d_in[2];
    const float* b1 = (const float*)d_in[3];
    const float* W2 = (const float*)d_in[4];
    const float* b2 = (const float*)d_in[5];
    float* out = (float*)d_out;

    char* ws = (char*)d_ws;
    const size_t K = (size_t)N_NODES * 4;  // 256 KB
    int*      flag         = (int*)ws;                          // 256 B
    unsigned* row_start    = (unsigned*)(ws + 256);             // K + 256 (65537)
    unsigned* H            = (unsigned*)(ws + 512 + K);         // K
    unsigned* P            = (unsigned*)(ws + 512 + 2 * K);     // K
    unsigned* bucket_start = (unsigned*)(ws + 512 + 3 * K);     // 1028 B (pad 2KB)
    int*      src_sorted   = (int*)(ws + 2560 + 3 * K);         // 4 MB
    unsigned* y32          = (unsigned*)(ws + 2560 + 3 * K + (size_t)N_EDGES * 4);  // 8 MB

    // pairs scratch lives in d_out: written by scatterA, consumed by bucketB,
    // then fully overwritten by spmm's h. Deterministic.
    unsigned* pairs = (unsigned*)d_out;

    detect_kernel<<<1, 64, 0, stream>>>((const unsigned*)ei, flag);
    histA_kernel<<<NB, 256, 0, stream>>>(ei, flag, H);
    scanH_kernel<<<1, 256, 0, stream>>>(H, P, bucket_start);
    scatterA_kernel<<<NB, 256, 0, stream>>>(ei, flag, P, bucket_start, pairs);
    bucketB_kernel<<<NB, 256, 0, stream>>>(pairs, bucket_start, x, row_start, src_sorted, y32);
    spmm_kernel<<<4096, 256, 0, stream>>>(src_sorted, row_start, y32, out);
    dense_mfma_kernel<<<1024, 256, 0, stream>>>(x, W1, b1, W2, b2, out);
}

// Round 8
// 102.706 us; speedup vs baseline: 1.5028x; 1.0906x over previous
//
#include <hip/hip_runtime.h>

#define N_NODES 65536
#define N_EDGES 1048576
#define D 64
#define NB 256                  // major buckets = dst >> 8
#define CHUNK (N_EDGES / NB)    // 4096 edges per histA/scatterA workgroup
#define SSTAGE 6144             // LDS staging capacity in bucketB (u16)

typedef __bf16 bf16x8 __attribute__((ext_vector_type(8)));
typedef float f32x4 __attribute__((ext_vector_type(4)));

__device__ __forceinline__ int edge_at(const void* ei, int is64, long long pos) {
    if (is64) return (int)((const long long*)ei)[pos];
    return ((const int*)ei)[pos];
}

// Inline int64/int32 detection: wave 0 ballots over the first 64 hi-words.
// (int64 values < 2^17 => hi word always 0; 64 consecutive zero odd-words in
// int32 index data has probability ~0.)
__device__ __forceinline__ int detect_is64(const unsigned* ei, int* s_is64) {
    if (threadIdx.x < 64) {
        unsigned v = ei[2 * threadIdx.x + 1];
        unsigned long long nz = __ballot(v != 0u);
        if (threadIdx.x == 0) *s_is64 = (nz == 0ull) ? 1 : 0;
    }
    __syncthreads();
    return *s_is64;
}

// Pass A1: per-chunk histogram over dst>>8. H layout: H[bucket*NB + wg].
__global__ __launch_bounds__(256) void histA_kernel(const void* ei,
                                                    unsigned* __restrict__ H) {
    __shared__ unsigned hist[NB];
    __shared__ int s_is64;
    const int is64 = detect_is64((const unsigned*)ei, &s_is64);
    const int t = threadIdx.x;
    const int w = blockIdx.x;
    hist[t] = 0;
    __syncthreads();
    const int base = w * CHUNK;
    for (int i = t; i < CHUNK; i += 256) {
        int dst = edge_at(ei, is64, (long long)N_EDGES + base + i);
        atomicAdd(&hist[dst >> 8], 1u);
    }
    __syncthreads();
    H[t * NB + w] = hist[t];
}

// Pass A2: one WG. Thread b: serial exclusive prefix over H[b][*] -> P[b][*],
// then block-scan of bucket totals -> bucket_start[257].
__global__ __launch_bounds__(256) void scanH_kernel(const unsigned* __restrict__ H,
                                                    unsigned* __restrict__ P,
                                                    unsigned* __restrict__ bucket_start) {
    __shared__ unsigned cs[NB];
    const int b = threadIdx.x;
    unsigned run = 0;
#pragma unroll 8
    for (int w = 0; w < NB; ++w) {
        P[b * NB + w] = run;
        run += H[b * NB + w];
    }
    unsigned own = run;
    cs[b] = run;
    __syncthreads();
    for (int off = 1; off < NB; off <<= 1) {
        unsigned v = (b >= off) ? cs[b - off] : 0u;
        __syncthreads();
        cs[b] += v;
        __syncthreads();
    }
    bucket_start[b] = cs[b] - own;
    if (b == NB - 1) bucket_start[NB] = cs[b];
}

// Pass A3: scatter edges into bucket-major order as packed u32:
// src in bits [0,16), dst&255 in bits [16,24). LDS cursors only.
__global__ __launch_bounds__(256) void scatterA_kernel(const void* ei,
                                                       const unsigned* __restrict__ P,
                                                       const unsigned* __restrict__ bucket_start,
                                                       unsigned* __restrict__ pairs) {
    __shared__ unsigned cur[NB];
    __shared__ int s_is64;
    const int is64 = detect_is64((const unsigned*)ei, &s_is64);
    const int t = threadIdx.x;
    const int w = blockIdx.x;
    cur[t] = bucket_start[t] + P[t * NB + w];
    __syncthreads();
    const int base = w * CHUNK;
    for (int i = t; i < CHUNK; i += 256) {
        int src = edge_at(ei, is64, base + i);
        int dst = edge_at(ei, is64, (long long)N_EDGES + base + i);
        unsigned pos = atomicAdd(&cur[dst >> 8], 1u);
        pairs[pos] = (unsigned)src | ((unsigned)(dst & 255) << 16);
    }
}

// Pass B: per major bucket: LDS histogram over dstlow (== deg, dense),
// LDS scan -> row_start, LDS-staged sort scatter -> coalesced u16 src16
// write-out, then prefolded y rows for this bucket's 256 nodes.
__global__ __launch_bounds__(256) void bucketB_kernel(const unsigned* __restrict__ pairs,
                                                      const unsigned* __restrict__ bucket_start,
                                                      const float* __restrict__ x,
                                                      unsigned* __restrict__ row_start,
                                                      unsigned short* __restrict__ src16,
                                                      unsigned* __restrict__ y32) {
    __shared__ unsigned hist[NB];
    __shared__ unsigned sc[NB];
    __shared__ unsigned degs[NB];
    __shared__ unsigned short s_src[SSTAGE];
    const int t = threadIdx.x;
    const int b = blockIdx.x;
    const unsigned base = bucket_start[b];
    const unsigned cnt = bucket_start[b + 1] - base;
    hist[t] = 0;
    __syncthreads();
    for (unsigned i = t; i < cnt; i += 256u) {
        atomicAdd(&hist[(pairs[base + i] >> 16) & 255u], 1u);
    }
    __syncthreads();
    const unsigned own = hist[t];
    degs[t] = own;
    sc[t] = own;
    __syncthreads();
    for (int off = 1; off < NB; off <<= 1) {
        unsigned v = (t >= off) ? sc[t - off] : 0u;
        __syncthreads();
        sc[t] += v;
        __syncthreads();
    }
    const unsigned excl = sc[t] - own;
    row_start[b * NB + t] = base + excl;
    if (b == NB - 1 && t == 0) row_start[N_NODES] = N_EDGES;
    hist[t] = excl;  // reuse as cursor
    __syncthreads();
    if (cnt <= SSTAGE) {
        for (unsigned i = t; i < cnt; i += 256u) {
            unsigned p = pairs[base + i];
            unsigned pos = atomicAdd(&hist[(p >> 16) & 255u], 1u);
            s_src[pos] = (unsigned short)(p & 0xFFFFu);
        }
        __syncthreads();
        for (unsigned i = t; i < cnt; i += 256u) src16[base + i] = s_src[i];
    } else {  // statistically unreachable fallback
        for (unsigned i = t; i < cnt; i += 256u) {
            unsigned p = pairs[base + i];
            unsigned pos = atomicAdd(&hist[(p >> 16) & 255u], 1u);
            src16[base + pos] = (unsigned short)(p & 0xFFFFu);
        }
    }
    // y phase: y[n][d] = bf16(rsqrt(deg[n]) * x[n][d]) for n in this bucket.
    const int nbase = b * NB;
    for (int idx = t; idx < NB * 32; idx += 256) {
        int nl = idx >> 5;
        int c = (idx & 31) * 2;
        unsigned d = degs[nl];
        float w = d ? rsqrtf((float)d) : 0.f;
        float2 v = *(const float2*)(x + (nbase + nl) * D + c);
        unsigned lo = (unsigned)__builtin_bit_cast(unsigned short, (__bf16)(v.x * w));
        unsigned hi = (unsigned)__builtin_bit_cast(unsigned short, (__bf16)(v.y * w));
        y32[(nbase + nl) * 32 + (idx & 31)] = lo | (hi << 16);
    }
}

// Atomic-free segmented SpMM over prefolded bf16 y.
// Wave = 8 groups x 8 lanes: group g handles edge slot g; lane r8 loads a
// uint4 (8 bf16 feats). 8 edges x 128B per iter, unrolled x2 (16 edges, 2
// outstanding 16B loads/lane). Combine via shfl_xor(8,16,32).
#define BLO(u) __uint_as_float((u) << 16)
#define BHI(u) __uint_as_float((u) & 0xffff0000u)
__global__ __launch_bounds__(256) void spmm_kernel(const unsigned short* __restrict__ src16,
                                                   const unsigned* __restrict__ row_start,
                                                   const uint4* __restrict__ y128,
                                                   float* __restrict__ h) {
    const int lane = threadIdx.x & 63;
    const int grp = lane >> 3;   // edge slot 0..7
    const int r8 = lane & 7;     // feature chunk: feats [8*r8, 8*r8+8)
    int wid = (blockIdx.x * blockDim.x + threadIdx.x) >> 6;
    int nw = (gridDim.x * blockDim.x) >> 6;
    for (int n = wid; n < N_NODES; n += nw) {
        const unsigned start = row_start[n];
        const unsigned end = row_start[n + 1];
        float a0 = 0.f, a1 = 0.f, a2 = 0.f, a3 = 0.f;
        float a4 = 0.f, a5 = 0.f, a6 = 0.f, a7 = 0.f;
        float c0 = 0.f, c1 = 0.f, c2 = 0.f, c3 = 0.f;
        float c4 = 0.f, c5 = 0.f, c6 = 0.f, c7 = 0.f;
        unsigned i = start;
        for (; i + 16 <= end; i += 16) {
            int sA = (int)src16[i + grp];
            int sB = (int)src16[i + 8 + grp];
            uint4 pA = y128[sA * 8 + r8];
            uint4 pB = y128[sB * 8 + r8];
            a0 += BLO(pA.x); a1 += BHI(pA.x);
            a2 += BLO(pA.y); a3 += BHI(pA.y);
            a4 += BLO(pA.z); a5 += BHI(pA.z);
            a6 += BLO(pA.w); a7 += BHI(pA.w);
            c0 += BLO(pB.x); c1 += BHI(pB.x);
            c2 += BLO(pB.y); c3 += BHI(pB.y);
            c4 += BLO(pB.z); c5 += BHI(pB.z);
            c6 += BLO(pB.w); c7 += BHI(pB.w);
        }
        for (; i < end; i += 8) {
            if (i + grp < end) {
                int s = (int)src16[i + grp];
                uint4 p = y128[s * 8 + r8];
                a0 += BLO(p.x); a1 += BHI(p.x);
                a2 += BLO(p.y); a3 += BHI(p.y);
                a4 += BLO(p.z); a5 += BHI(p.z);
                a6 += BLO(p.w); a7 += BHI(p.w);
            }
        }
        a0 += c0; a1 += c1; a2 += c2; a3 += c3;
        a4 += c4; a5 += c5; a6 += c6; a7 += c7;
        a0 += __shfl_xor(a0, 8); a0 += __shfl_xor(a0, 16); a0 += __shfl_xor(a0, 32);
        a1 += __shfl_xor(a1, 8); a1 += __shfl_xor(a1, 16); a1 += __shfl_xor(a1, 32);
        a2 += __shfl_xor(a2, 8); a2 += __shfl_xor(a2, 16); a2 += __shfl_xor(a2, 32);
        a3 += __shfl_xor(a3, 8); a3 += __shfl_xor(a3, 16); a3 += __shfl_xor(a3, 32);
        a4 += __shfl_xor(a4, 8); a4 += __shfl_xor(a4, 16); a4 += __shfl_xor(a4, 32);
        a5 += __shfl_xor(a5, 8); a5 += __shfl_xor(a5, 16); a5 += __shfl_xor(a5, 32);
        a6 += __shfl_xor(a6, 8); a6 += __shfl_xor(a6, 16); a6 += __shfl_xor(a6, 32);
        a7 += __shfl_xor(a7, 8); a7 += __shfl_xor(a7, 16); a7 += __shfl_xor(a7, 32);
        const float w = (end > start) ? rsqrtf((float)(end - start)) : 0.f;
        if (grp == 0) {
            float4 v0 = make_float4(a0 * w, a1 * w, a2 * w, a3 * w);
            float4 v1 = make_float4(a4 * w, a5 * w, a6 * w, a7 * w);
            *(float4*)(h + n * D + r8 * 8) = v0;
            *(float4*)(h + n * D + r8 * 8 + 4) = v1;
        }
    }
}

// out = leaky(h@W1+b1) + leaky((x*h)@W2+b2) via mfma_f32_16x16x32_bf16.
__global__ __launch_bounds__(256) void dense_mfma_kernel(const float* __restrict__ x,
                                                         const float* __restrict__ W1,
                                                         const float* __restrict__ b1,
                                                         const float* __restrict__ W2,
                                                         const float* __restrict__ b2,
                                                         float* hout) {
    const int lane = threadIdx.x & 63;
    const int lo = lane & 15;
    const int hi = lane >> 4;

    bf16x8 bw1[2][4], bw2[2][4];
#pragma unroll
    for (int kt = 0; kt < 2; ++kt)
#pragma unroll
        for (int nt = 0; nt < 4; ++nt) {
            bf16x8 v1, v2;
#pragma unroll
            for (int j = 0; j < 8; ++j) {
                int k = kt * 32 + hi * 8 + j;
                int n = nt * 16 + lo;
                v1[j] = (__bf16)W1[k * D + n];
                v2[j] = (__bf16)W2[k * D + n];
            }
            bw1[kt][nt] = v1;
            bw2[kt][nt] = v2;
        }
    float bb1[4], bb2[4];
#pragma unroll
    for (int nt = 0; nt < 4; ++nt) {
        bb1[nt] = b1[nt * 16 + lo];
        bb2[nt] = b2[nt * 16 + lo];
    }

    int wid = (blockIdx.x * blockDim.x + threadIdx.x) >> 6;
    int nw = (gridDim.x * blockDim.x) >> 6;
    for (int blk = wid; blk < N_NODES / 16; blk += nw) {
        const int rb = blk * 16;
        const float* hrow = hout + (rb + lo) * D;
        const float* xrow = x + (rb + lo) * D;
        bf16x8 ah[2], ag[2];
#pragma unroll
        for (int kt = 0; kt < 2; ++kt) {
            const int c = kt * 32 + hi * 8;
            float4 hv0 = *(const float4*)(hrow + c);
            float4 hv1 = *(const float4*)(hrow + c + 4);
            float4 xv0 = *(const float4*)(xrow + c);
            float4 xv1 = *(const float4*)(xrow + c + 4);
            bf16x8 a, g;
            a[0] = (__bf16)hv0.x; g[0] = (__bf16)(hv0.x * xv0.x);
            a[1] = (__bf16)hv0.y; g[1] = (__bf16)(hv0.y * xv0.y);
            a[2] = (__bf16)hv0.z; g[2] = (__bf16)(hv0.z * xv0.z);
            a[3] = (__bf16)hv0.w; g[3] = (__bf16)(hv0.w * xv0.w);
            a[4] = (__bf16)hv1.x; g[4] = (__bf16)(hv1.x * xv1.x);
            a[5] = (__bf16)hv1.y; g[5] = (__bf16)(hv1.y * xv1.y);
            a[6] = (__bf16)hv1.z; g[6] = (__bf16)(hv1.z * xv1.z);
            a[7] = (__bf16)hv1.w; g[7] = (__bf16)(hv1.w * xv1.w);
            ah[kt] = a;
            ag[kt] = g;
        }
        f32x4 acc1[4], acc2[4];
#pragma unroll
        for (int nt = 0; nt < 4; ++nt) {
            acc1[nt] = (f32x4){0.f, 0.f, 0.f, 0.f};
            acc2[nt] = (f32x4){0.f, 0.f, 0.f, 0.f};
        }
#pragma unroll
        for (int kt = 0; kt < 2; ++kt)
#pragma unroll
            for (int nt = 0; nt < 4; ++nt) {
                acc1[nt] = __builtin_amdgcn_mfma_f32_16x16x32_bf16(ah[kt], bw1[kt][nt], acc1[nt], 0, 0, 0);
                acc2[nt] = __builtin_amdgcn_mfma_f32_16x16x32_bf16(ag[kt], bw2[kt][nt], acc2[nt], 0, 0, 0);
            }
#pragma unroll
        for (int nt = 0; nt < 4; ++nt)
#pragma unroll
            for (int r = 0; r < 4; ++r) {
                float a1 = acc1[nt][r] + bb1[nt];
                float a2 = acc2[nt][r] + bb2[nt];
                a1 = (a1 >= 0.f) ? a1 : 0.2f * a1;
                a2 = (a2 >= 0.f) ? a2 : 0.2f * a2;
                hout[(rb + hi * 4 + r) * D + nt * 16 + lo] = a1 + a2;
            }
    }
}

extern "C" void kernel_launch(void* const* d_in, const int* in_sizes, int n_in,
                              void* d_out, int out_size, void* d_ws, size_t ws_size,
                              hipStream_t stream) {
    const float* x  = (const float*)d_in[0];
    const void*  ei = d_in[1];
    const float* W1 = (const float*)d_in[2];
    const float* b1 = (const float*)d_in[3];
    const float* W2 = (const float*)d_in[4];
    const float* b2 = (const float*)d_in[5];
    float* out = (float*)d_out;

    char* ws = (char*)d_ws;
    const size_t K = (size_t)N_NODES * 4;  // 256 KB
    unsigned*       row_start    = (unsigned*)(ws + 256);          // K + 256 (65537)
    unsigned*       H            = (unsigned*)(ws + 512 + K);      // K
    unsigned*       P            = (unsigned*)(ws + 512 + 2 * K);  // K
    unsigned*       bucket_start = (unsigned*)(ws + 512 + 3 * K);  // 1028 B (pad 2KB)
    unsigned short* src16        = (unsigned short*)(ws + 2560 + 3 * K);  // 2 MB
    unsigned*       y32          = (unsigned*)(ws + 2560 + 3 * K + (size_t)N_EDGES * 2);  // 8 MB

    // pairs scratch lives in d_out: written by scatterA, consumed by bucketB,
    // then fully overwritten by spmm's h. Deterministic.
    unsigned* pairs = (unsigned*)d_out;

    histA_kernel<<<NB, 256, 0, stream>>>(ei, H);
    scanH_kernel<<<1, 256, 0, stream>>>(H, P, bucket_start);
    scatterA_kernel<<<NB, 256, 0, stream>>>(ei, P, bucket_start, pairs);
    bucketB_kernel<<<NB, 256, 0, stream>>>(pairs, bucket_start, x, row_start, src16, y32);
    spmm_kernel<<<4096, 256, 0, stream>>>(src16, row_start, (const uint4*)y32, out);
    dense_mfma_kernel<<<1024, 256, 0, stream>>>(x, W1, b1, W2, b2, out);
}

// Round 9
// 82.886 us; speedup vs baseline: 1.8622x; 1.2391x over previous
//
#include <hip/hip_runtime.h>

#define N_NODES 65536
#define N_EDGES 1048576
#define D 64
#define NB 256                  // major buckets = dst >> 8
#define CHUNK (N_EDGES / NB)    // 4096 edges per passA workgroup
#define SSTAGE 6144             // LDS staging capacity in bucketB
#define FBCAP 65536             // fallback capacity per bucket (ws scratch)

typedef __bf16 bf16x8 __attribute__((ext_vector_type(8)));
typedef float f32x4 __attribute__((ext_vector_type(4)));

__device__ __forceinline__ int edge_at(const void* ei, int is64, long long pos) {
    if (is64) return (int)((const long long*)ei)[pos];
    return ((const int*)ei)[pos];
}

// Inline int64/int32 detection (hi word of int64 indices < 2^17 is always 0).
__device__ __forceinline__ int detect_is64(const unsigned* ei, int* s_is64) {
    if (threadIdx.x < 64) {
        unsigned v = ei[2 * threadIdx.x + 1];
        unsigned long long nz = __ballot(v != 0u);
        if (threadIdx.x == 0) *s_is64 = (nz == 0ull) ? 1 : 0;
    }
    __syncthreads();
    return *s_is64;
}

// ---------------------------------------------------------------------------
// Pass A (single pass over edges): stage chunk in LDS packed (src | dst<<16),
// LDS hist over dst>>8, LDS scan, LDS bucket-sort, coalesced write-out.
// Emits: pairs_cs[w*CHUNK + i] (chunk-sorted pairs), H[b*NB+w], L[b*NB+w].
// ---------------------------------------------------------------------------
__global__ __launch_bounds__(256) void passA_kernel(const void* ei,
                                                    unsigned* __restrict__ H,
                                                    unsigned* __restrict__ L,
                                                    unsigned* __restrict__ pairs_cs) {
    __shared__ unsigned ed[CHUNK];
    __shared__ unsigned srt[CHUNK];
    __shared__ unsigned hist[NB];
    __shared__ unsigned scn[NB];
    __shared__ int s_is64;
    const int is64 = detect_is64((const unsigned*)ei, &s_is64);
    const int t = threadIdx.x;
    const int w = blockIdx.x;
    hist[t] = 0;
    __syncthreads();
    const int base = w * CHUNK;
    for (int i = t; i < CHUNK; i += 256) {
        unsigned src = (unsigned)edge_at(ei, is64, base + i);
        unsigned dst = (unsigned)edge_at(ei, is64, (long long)N_EDGES + base + i);
        ed[i] = src | (dst << 16);
        atomicAdd(&hist[dst >> 8], 1u);
    }
    __syncthreads();
    const unsigned own = hist[t];
    scn[t] = own;
    __syncthreads();
    for (int off = 1; off < NB; off <<= 1) {
        unsigned v = (t >= off) ? scn[t - off] : 0u;
        __syncthreads();
        scn[t] += v;
        __syncthreads();
    }
    const unsigned excl = scn[t] - own;
    H[t * NB + w] = own;
    L[t * NB + w] = excl;
    hist[t] = excl;  // reuse as cursor
    __syncthreads();
    for (int i = t; i < CHUNK; i += 256) {
        unsigned p = ed[i];
        unsigned pos = atomicAdd(&hist[p >> 24], 1u);  // bucket = dst>>8 = p>>24
        srt[pos] = p;
    }
    __syncthreads();
    for (int i = t; i < CHUNK; i += 256) pairs_cs[(size_t)w * CHUNK + i] = srt[i];
}

// Tiny scan: bucket totals (sum of H row) -> bucket_start[257].
__global__ __launch_bounds__(256) void scanT_kernel(const unsigned* __restrict__ H,
                                                    unsigned* __restrict__ bucket_start) {
    __shared__ unsigned cs[NB];
    const int t = threadIdx.x;
    const uint4* Hr = (const uint4*)(H + t * NB);
    unsigned tot = 0;
#pragma unroll 8
    for (int k = 0; k < NB / 4; ++k) {
        uint4 q = Hr[k];
        tot += q.x + q.y + q.z + q.w;
    }
    const unsigned own = tot;
    cs[t] = own;
    __syncthreads();
    for (int off = 1; off < NB; off <<= 1) {
        unsigned v = (t >= off) ? cs[t - off] : 0u;
        __syncthreads();
        cs[t] += v;
        __syncthreads();
    }
    bucket_start[t] = cs[t] - own;
    if (t == NB - 1) bucket_start[NB] = cs[t];
}

// ---------------------------------------------------------------------------
// Pass B: gather this bucket's 256 chunk-runs into LDS, hist over dstlow
// (== deg, dense), LDS scan -> row_start, LDS sort -> coalesced u16 src16,
// then prefolded y rows for this bucket's 256 nodes.
// ---------------------------------------------------------------------------
__global__ __launch_bounds__(256) void bucketB_kernel(const unsigned* __restrict__ pairs_cs,
                                                      const unsigned* __restrict__ H,
                                                      const unsigned* __restrict__ L,
                                                      const unsigned* __restrict__ bucket_start,
                                                      const float* __restrict__ x,
                                                      unsigned* __restrict__ row_start,
                                                      unsigned short* __restrict__ src16,
                                                      unsigned* __restrict__ y32,
                                                      unsigned* __restrict__ fb) {
    __shared__ unsigned s_pairs[SSTAGE];
    __shared__ unsigned short s_src[SSTAGE];
    __shared__ unsigned hist[NB];
    __shared__ unsigned scn[NB];
    __shared__ unsigned degs[NB];
    const int t = threadIdx.x;
    const int b = blockIdx.x;
    const unsigned base = bucket_start[b];
    const unsigned cnt = bucket_start[b + 1] - base;
    const bool staged = (cnt <= SSTAGE);

    // run-gather: thread t copies chunk t's run for this bucket.
    const unsigned Hb = H[b * NB + t];
    const unsigned Lb = L[b * NB + t];
    scn[t] = Hb;
    __syncthreads();
    for (int off = 1; off < NB; off <<= 1) {
        unsigned v = (t >= off) ? scn[t - off] : 0u;
        __syncthreads();
        scn[t] += v;
        __syncthreads();
    }
    const unsigned ex = scn[t] - Hb;
    unsigned* wp = staged ? s_pairs : (fb + (size_t)b * FBCAP);
    for (unsigned j = 0; j < Hb; ++j) wp[ex + j] = pairs_cs[(size_t)t * CHUNK + Lb + j];
    __syncthreads();
    const unsigned* pp = staged ? s_pairs : (fb + (size_t)b * FBCAP);

    hist[t] = 0;
    __syncthreads();
    for (unsigned i = t; i < cnt; i += 256u) {
        atomicAdd(&hist[(pp[i] >> 16) & 255u], 1u);
    }
    __syncthreads();
    const unsigned own = hist[t];
    degs[t] = own;
    scn[t] = own;
    __syncthreads();
    for (int off = 1; off < NB; off <<= 1) {
        unsigned v = (t >= off) ? scn[t - off] : 0u;
        __syncthreads();
        scn[t] += v;
        __syncthreads();
    }
    const unsigned excl = scn[t] - own;
    row_start[b * NB + t] = base + excl;
    if (b == NB - 1 && t == 0) row_start[N_NODES] = N_EDGES;
    hist[t] = excl;  // reuse as cursor
    __syncthreads();
    if (staged) {
        for (unsigned i = t; i < cnt; i += 256u) {
            unsigned p = pp[i];
            unsigned pos = atomicAdd(&hist[(p >> 16) & 255u], 1u);
            s_src[pos] = (unsigned short)(p & 0xFFFFu);
        }
        __syncthreads();
        for (unsigned i = t; i < cnt; i += 256u) src16[base + i] = s_src[i];
    } else {  // statistically unreachable
        for (unsigned i = t; i < cnt; i += 256u) {
            unsigned p = pp[i];
            unsigned pos = atomicAdd(&hist[(p >> 16) & 255u], 1u);
            src16[base + pos] = (unsigned short)(p & 0xFFFFu);
        }
    }
    // y phase: y[n][d] = bf16(rsqrt(deg[n]) * x[n][d]) for this bucket.
    const int nbase = b * NB;
    for (int idx = t; idx < NB * 32; idx += 256) {
        int nl = idx >> 5;
        int c = (idx & 31) * 2;
        unsigned d = degs[nl];
        float w = d ? rsqrtf((float)d) : 0.f;
        float2 v = *(const float2*)(x + (nbase + nl) * D + c);
        unsigned lo = (unsigned)__builtin_bit_cast(unsigned short, (__bf16)(v.x * w));
        unsigned hi = (unsigned)__builtin_bit_cast(unsigned short, (__bf16)(v.y * w));
        y32[(nbase + nl) * 32 + (idx & 31)] = lo | (hi << 16);
    }
}

// Atomic-free segmented SpMM over prefolded bf16 y; h stored packed bf16.
#define BLO(u) __uint_as_float((u) << 16)
#define BHI(u) __uint_as_float((u) & 0xffff0000u)
__device__ __forceinline__ unsigned pkbf(float lo, float hi) {
    return (unsigned)__builtin_bit_cast(unsigned short, (__bf16)lo) |
           ((unsigned)__builtin_bit_cast(unsigned short, (__bf16)hi) << 16);
}
__global__ __launch_bounds__(256) void spmm_kernel(const unsigned short* __restrict__ src16,
                                                   const unsigned* __restrict__ row_start,
                                                   const uint4* __restrict__ y128,
                                                   uint4* __restrict__ hb4) {
    const int lane = threadIdx.x & 63;
    const int grp = lane >> 3;   // edge slot 0..7
    const int r8 = lane & 7;     // feature chunk [8*r8, 8*r8+8)
    int wid = (blockIdx.x * blockDim.x + threadIdx.x) >> 6;
    int nw = (gridDim.x * blockDim.x) >> 6;
    for (int n = wid; n < N_NODES; n += nw) {
        const unsigned start = row_start[n];
        const unsigned end = row_start[n + 1];
        float a0 = 0.f, a1 = 0.f, a2 = 0.f, a3 = 0.f;
        float a4 = 0.f, a5 = 0.f, a6 = 0.f, a7 = 0.f;
        float c0 = 0.f, c1 = 0.f, c2 = 0.f, c3 = 0.f;
        float c4 = 0.f, c5 = 0.f, c6 = 0.f, c7 = 0.f;
        unsigned i = start;
        for (; i + 16 <= end; i += 16) {
            int sA = (int)src16[i + grp];
            int sB = (int)src16[i + 8 + grp];
            uint4 pA = y128[sA * 8 + r8];
            uint4 pB = y128[sB * 8 + r8];
            a0 += BLO(pA.x); a1 += BHI(pA.x);
            a2 += BLO(pA.y); a3 += BHI(pA.y);
            a4 += BLO(pA.z); a5 += BHI(pA.z);
            a6 += BLO(pA.w); a7 += BHI(pA.w);
            c0 += BLO(pB.x); c1 += BHI(pB.x);
            c2 += BLO(pB.y); c3 += BHI(pB.y);
            c4 += BLO(pB.z); c5 += BHI(pB.z);
            c6 += BLO(pB.w); c7 += BHI(pB.w);
        }
        for (; i < end; i += 8) {
            if (i + grp < end) {
                int s = (int)src16[i + grp];
                uint4 p = y128[s * 8 + r8];
                a0 += BLO(p.x); a1 += BHI(p.x);
                a2 += BLO(p.y); a3 += BHI(p.y);
                a4 += BLO(p.z); a5 += BHI(p.z);
                a6 += BLO(p.w); a7 += BHI(p.w);
            }
        }
        a0 += c0; a1 += c1; a2 += c2; a3 += c3;
        a4 += c4; a5 += c5; a6 += c6; a7 += c7;
        a0 += __shfl_xor(a0, 8); a0 += __shfl_xor(a0, 16); a0 += __shfl_xor(a0, 32);
        a1 += __shfl_xor(a1, 8); a1 += __shfl_xor(a1, 16); a1 += __shfl_xor(a1, 32);
        a2 += __shfl_xor(a2, 8); a2 += __shfl_xor(a2, 16); a2 += __shfl_xor(a2, 32);
        a3 += __shfl_xor(a3, 8); a3 += __shfl_xor(a3, 16); a3 += __shfl_xor(a3, 32);
        a4 += __shfl_xor(a4, 8); a4 += __shfl_xor(a4, 16); a4 += __shfl_xor(a4, 32);
        a5 += __shfl_xor(a5, 8); a5 += __shfl_xor(a5, 16); a5 += __shfl_xor(a5, 32);
        a6 += __shfl_xor(a6, 8); a6 += __shfl_xor(a6, 16); a6 += __shfl_xor(a6, 32);
        a7 += __shfl_xor(a7, 8); a7 += __shfl_xor(a7, 16); a7 += __shfl_xor(a7, 32);
        const float w = (end > start) ? rsqrtf((float)(end - start)) : 0.f;
        if (grp == 0) {
            uint4 v;
            v.x = pkbf(a0 * w, a1 * w);
            v.y = pkbf(a2 * w, a3 * w);
            v.z = pkbf(a4 * w, a5 * w);
            v.w = pkbf(a6 * w, a7 * w);
            hb4[n * 8 + r8] = v;
        }
    }
}

// out = leaky(h@W1+b1) + leaky((x*h)@W2+b2) via mfma_f32_16x16x32_bf16.
// h read as packed bf16 (A-frag bits used directly).
__global__ __launch_bounds__(256) void dense_mfma_kernel(const float* __restrict__ x,
                                                         const uint4* __restrict__ hb4,
                                                         const float* __restrict__ W1,
                                                         const float* __restrict__ b1,
                                                         const float* __restrict__ W2,
                                                         const float* __restrict__ b2,
                                                         float* __restrict__ out) {
    const int lane = threadIdx.x & 63;
    const int lo = lane & 15;
    const int hi = lane >> 4;

    bf16x8 bw1[2][4], bw2[2][4];
#pragma unroll
    for (int kt = 0; kt < 2; ++kt)
#pragma unroll
        for (int nt = 0; nt < 4; ++nt) {
            bf16x8 v1, v2;
#pragma unroll
            for (int j = 0; j < 8; ++j) {
                int k = kt * 32 + hi * 8 + j;
                int n = nt * 16 + lo;
                v1[j] = (__bf16)W1[k * D + n];
                v2[j] = (__bf16)W2[k * D + n];
            }
            bw1[kt][nt] = v1;
            bw2[kt][nt] = v2;
        }
    float bb1[4], bb2[4];
#pragma unroll
    for (int nt = 0; nt < 4; ++nt) {
        bb1[nt] = b1[nt * 16 + lo];
        bb2[nt] = b2[nt * 16 + lo];
    }

    int wid = (blockIdx.x * blockDim.x + threadIdx.x) >> 6;
    int nw = (gridDim.x * blockDim.x) >> 6;
    for (int blk = wid; blk < N_NODES / 16; blk += nw) {
        const int rb = blk * 16;
        const uint4* hrow = hb4 + (rb + lo) * 8;
        const float* xrow = x + (rb + lo) * D;
        bf16x8 ah[2], ag[2];
#pragma unroll
        for (int kt = 0; kt < 2; ++kt) {
            const int c = kt * 32 + hi * 8;
            uint4 hp = hrow[kt * 4 + hi];
            float4 xv0 = *(const float4*)(xrow + c);
            float4 xv1 = *(const float4*)(xrow + c + 4);
            ah[kt] = __builtin_bit_cast(bf16x8, hp);
            bf16x8 g;
            g[0] = (__bf16)(BLO(hp.x) * xv0.x);
            g[1] = (__bf16)(BHI(hp.x) * xv0.y);
            g[2] = (__bf16)(BLO(hp.y) * xv0.z);
            g[3] = (__bf16)(BHI(hp.y) * xv0.w);
            g[4] = (__bf16)(BLO(hp.z) * xv1.x);
            g[5] = (__bf16)(BHI(hp.z) * xv1.y);
            g[6] = (__bf16)(BLO(hp.w) * xv1.z);
            g[7] = (__bf16)(BHI(hp.w) * xv1.w);
            ag[kt] = g;
        }
        f32x4 acc1[4], acc2[4];
#pragma unroll
        for (int nt = 0; nt < 4; ++nt) {
            acc1[nt] = (f32x4){0.f, 0.f, 0.f, 0.f};
            acc2[nt] = (f32x4){0.f, 0.f, 0.f, 0.f};
        }
#pragma unroll
        for (int kt = 0; kt < 2; ++kt)
#pragma unroll
            for (int nt = 0; nt < 4; ++nt) {
                acc1[nt] = __builtin_amdgcn_mfma_f32_16x16x32_bf16(ah[kt], bw1[kt][nt], acc1[nt], 0, 0, 0);
                acc2[nt] = __builtin_amdgcn_mfma_f32_16x16x32_bf16(ag[kt], bw2[kt][nt], acc2[nt], 0, 0, 0);
            }
#pragma unroll
        for (int nt = 0; nt < 4; ++nt)
#pragma unroll
            for (int r = 0; r < 4; ++r) {
                float a1 = acc1[nt][r] + bb1[nt];
                float a2 = acc2[nt][r] + bb2[nt];
                a1 = (a1 >= 0.f) ? a1 : 0.2f * a1;
                a2 = (a2 >= 0.f) ? a2 : 0.2f * a2;
                out[(rb + hi * 4 + r) * D + nt * 16 + lo] = a1 + a2;
            }
    }
}

extern "C" void kernel_launch(void* const* d_in, const int* in_sizes, int n_in,
                              void* d_out, int out_size, void* d_ws, size_t ws_size,
                              hipStream_t stream) {
    const float* x  = (const float*)d_in[0];
    const void*  ei = d_in[1];
    const float* W1 = (const float*)d_in[2];
    const float* b1 = (const float*)d_in[3];
    const float* W2 = (const float*)d_in[4];
    const float* b2 = (const float*)d_in[5];
    float* out = (float*)d_out;

    char* p = (char*)d_ws;
    unsigned* bucket_start = (unsigned*)p;       p += 4096;            // 257 u32
    unsigned* row_start    = (unsigned*)p;       p += 266240;          // 65537 u32
    unsigned* H            = (unsigned*)p;       p += NB * NB * 4;     // 256 KB
    unsigned* L            = (unsigned*)p;       p += NB * NB * 4;     // 256 KB
    unsigned short* src16  = (unsigned short*)p; p += (size_t)N_EDGES * 2;     // 2 MB
    unsigned* y32          = (unsigned*)p;       p += (size_t)N_NODES * 32 * 4; // 8 MB
    unsigned* hb           = (unsigned*)p;       p += (size_t)N_NODES * 32 * 4; // 8 MB
    unsigned* fb           = (unsigned*)p;       // 64 MB fallback (rarely touched)

    // pairs_cs scratch lives in d_out: written by passA, consumed by bucketB,
    // then d_out is fully overwritten by dense_mfma. Deterministic modulo
    // intra-run LDS-atomic order (rounding-level only, as in prior rounds).
    unsigned* pairs_cs = (unsigned*)d_out;

    passA_kernel<<<NB, 256, 0, stream>>>(ei, H, L, pairs_cs);
    scanT_kernel<<<1, 256, 0, stream>>>(H, bucket_start);
    bucketB_kernel<<<NB, 256, 0, stream>>>(pairs_cs, H, L, bucket_start, x,
                                           row_start, src16, y32, fb);
    spmm_kernel<<<4096, 256, 0, stream>>>(src16, row_start, (const uint4*)y32, (uint4*)hb);
    dense_mfma_kernel<<<1024, 256, 0, stream>>>(x, (const uint4*)hb, W1, b1, W2, b2, out);
}